// Round 1
// baseline (170.542 us; speedup 1.0000x reference)
//
#include <hip/hip_runtime.h>
#include <hip/hip_bf16.h>

#define LNUM 13
#define FDIM 768
#define SDIM 512
#define BNUM 32
#define H1DIM 512
#define H2DIM 256

// ---------------- Kernel A: per-tile partial sum / sumsq of layer-weighted word vectors
__global__ __launch_bounds__(192) void kA_partials(
    const float* __restrict__ x, const int* __restrict__ lengths,
    const float* __restrict__ lw, float* __restrict__ partial,
    int NT, int TS) {
  const int b = blockIdx.x / NT;
  const int t = blockIdx.x % NT;

  __shared__ float w[LNUM];
  if (threadIdx.x == 0) {
    float m = lw[0];
    #pragma unroll
    for (int l = 1; l < LNUM; ++l) m = fmaxf(m, lw[l]);
    float e[LNUM]; float s = 0.f;
    #pragma unroll
    for (int l = 0; l < LNUM; ++l) { e[l] = expf(lw[l] - m); s += e[l]; }
    #pragma unroll
    for (int l = 0; l < LNUM; ++l) w[l] = e[l] / s;
  }
  __syncthreads();

  const int len = lengths[b];
  const int s0 = t * TS;
  const int s1 = min(s0 + TS, len);

  float4 sum = make_float4(0.f, 0.f, 0.f, 0.f);
  float4 sq  = make_float4(0.f, 0.f, 0.f, 0.f);

  // thread covers 4 consecutive floats of F: f = 4*tid .. 4*tid+3 (192*4 = 768)
  const float* xb = x + ((size_t)b * SDIM) * LNUM * FDIM + (size_t)threadIdx.x * 4;

  for (int s = s0; s < s1; ++s) {
    const float* xs = xb + (size_t)s * LNUM * FDIM;
    float4 word = make_float4(0.f, 0.f, 0.f, 0.f);
    #pragma unroll
    for (int l = 0; l < LNUM; ++l) {
      float4 v = *reinterpret_cast<const float4*>(xs + (size_t)l * FDIM);
      const float wl = w[l];
      word.x = fmaf(wl, v.x, word.x);
      word.y = fmaf(wl, v.y, word.y);
      word.z = fmaf(wl, v.z, word.z);
      word.w = fmaf(wl, v.w, word.w);
    }
    sum.x += word.x; sum.y += word.y; sum.z += word.z; sum.w += word.w;
    sq.x = fmaf(word.x, word.x, sq.x);
    sq.y = fmaf(word.y, word.y, sq.y);
    sq.z = fmaf(word.z, word.z, sq.z);
    sq.w = fmaf(word.w, word.w, sq.w);
  }

  float* p = partial + ((size_t)(b * NT + t) * 2) * FDIM + (size_t)threadIdx.x * 4;
  *reinterpret_cast<float4*>(p) = sum;
  *reinterpret_cast<float4*>(p + FDIM) = sq;
}

// ---------------- Kernel B: reduce partials -> mean/std feats [B, 2F]
__global__ __launch_bounds__(FDIM) void kB_stats(
    const float* __restrict__ partial, const int* __restrict__ lengths,
    float* __restrict__ feats, int NT) {
  const int b = blockIdx.x;
  const int t = threadIdx.x;  // 0..767
  float msum = 0.f, msq = 0.f;
  for (int tt = 0; tt < NT; ++tt) {
    const float* p = partial + ((size_t)(b * NT + tt) * 2) * FDIM;
    msum += p[t];
    msq  += p[FDIM + t];
  }
  const int n = lengths[b];
  const float fn = (float)n;
  const float mean = msum / fmaxf(fn, 1.f);
  const float var = (msq - fn * mean * mean) / fmaxf(fn - 1.f, 1.f);
  const float sd = (n > 1) ? sqrtf(fmaxf(var, 0.f)) : 0.f;
  feats[(size_t)b * 2 * FDIM + t] = mean;
  feats[(size_t)b * 2 * FDIM + FDIM + t] = sd;
}

// ---------------- Kernel C: h1 = relu(feats @ W1 + b1), grid = B * 4 col-tiles, 128 thr
__global__ __launch_bounds__(128) void kC_fc1(
    const float* __restrict__ feats, const float* __restrict__ W1,
    const float* __restrict__ b1, float* __restrict__ h1) {
  const int b  = blockIdx.x >> 2;
  const int jt = blockIdx.x & 3;
  __shared__ float fs[2 * FDIM];
  for (int i = threadIdx.x; i < 2 * FDIM; i += 128)
    fs[i] = feats[(size_t)b * 2 * FDIM + i];
  __syncthreads();
  const int j = jt * 128 + threadIdx.x;
  float acc = b1[j];
  #pragma unroll 8
  for (int k = 0; k < 2 * FDIM; ++k)
    acc = fmaf(fs[k], W1[(size_t)k * H1DIM + j], acc);
  h1[(size_t)b * H1DIM + j] = fmaxf(acc, 0.f);
}

// ---------------- Kernel D: h2 = relu(h1 @ W2 + b2); out = h2 @ W3 + b3
__global__ __launch_bounds__(H2DIM) void kD_fc23(
    const float* __restrict__ h1, const float* __restrict__ W2,
    const float* __restrict__ b2, const float* __restrict__ W3,
    const float* __restrict__ b3, float* __restrict__ out) {
  const int b = blockIdx.x;
  const int t = threadIdx.x;  // 0..255
  __shared__ float hs[H1DIM];
  for (int i = t; i < H1DIM; i += H2DIM)
    hs[i] = h1[(size_t)b * H1DIM + i];
  __syncthreads();
  float acc = b2[t];
  #pragma unroll 8
  for (int k = 0; k < H1DIM; ++k)
    acc = fmaf(hs[k], W2[(size_t)k * H2DIM + t], acc);
  const float h2 = fmaxf(acc, 0.f);
  float v = h2 * W3[t];
  // wave (64-lane) reduce, then across 4 waves via LDS
  #pragma unroll
  for (int off = 32; off > 0; off >>= 1) v += __shfl_down(v, off, 64);
  __shared__ float wred[4];
  if ((t & 63) == 0) wred[t >> 6] = v;
  __syncthreads();
  if (t == 0) out[b] = wred[0] + wred[1] + wred[2] + wred[3] + b3[0];
}

extern "C" void kernel_launch(void* const* d_in, const int* in_sizes, int n_in,
                              void* d_out, int out_size, void* d_ws, size_t ws_size,
                              hipStream_t stream) {
  const float* x       = (const float*)d_in[0];
  const int*   lengths = (const int*)  d_in[1];
  const float* lw      = (const float*)d_in[2];
  const float* W1      = (const float*)d_in[3];
  const float* b1      = (const float*)d_in[4];
  const float* W2      = (const float*)d_in[5];
  const float* b2      = (const float*)d_in[6];
  const float* W3      = (const float*)d_in[7];
  const float* b3      = (const float*)d_in[8];
  float* out = (float*)d_out;

  // pick NT (tiles over S) to fit workspace
  int NT = 32;
  size_t need;
  for (;;) {
    need = ((size_t)BNUM * NT * 2 * FDIM + (size_t)BNUM * 2 * FDIM +
            (size_t)BNUM * H1DIM) * sizeof(float);
    if (need <= ws_size || NT == 1) break;
    NT >>= 1;
  }
  const int TS = (SDIM + NT - 1) / NT;

  float* partial = (float*)d_ws;
  float* feats   = partial + (size_t)BNUM * NT * 2 * FDIM;
  float* h1      = feats + (size_t)BNUM * 2 * FDIM;

  kA_partials<<<dim3(BNUM * NT), dim3(192), 0, stream>>>(x, lengths, lw, partial, NT, TS);
  kB_stats<<<dim3(BNUM), dim3(FDIM), 0, stream>>>(partial, lengths, feats, NT);
  kC_fc1<<<dim3(BNUM * 4), dim3(128), 0, stream>>>(feats, W1, b1, h1);
  kD_fc23<<<dim3(BNUM), dim3(H2DIM), 0, stream>>>(h1, W2, b2, W3, b3, out);
}

// Round 2
// 167.452 us; speedup vs baseline: 1.0185x; 1.0185x over previous
//
#include <hip/hip_runtime.h>
#include <hip/hip_bf16.h>

#define LNUM 13
#define FDIM 768
#define SDIM 512
#define BNUM 32
#define H1DIM 512
#define H2DIM 256

// ---------------- Kernel A: per-tile partial sum / sumsq of layer-weighted word vectors
// Block (b, t) handles s = t, t+NT, t+2NT, ... < len  (balanced within each b)
__global__ __launch_bounds__(192) void kA_partials(
    const float* __restrict__ x, const int* __restrict__ lengths,
    const float* __restrict__ lw, float* __restrict__ partial, int NT) {
  const int b = blockIdx.x / NT;
  const int t = blockIdx.x % NT;

  __shared__ float w[LNUM];
  if (threadIdx.x == 0) {
    float m = lw[0];
    #pragma unroll
    for (int l = 1; l < LNUM; ++l) m = fmaxf(m, lw[l]);
    float e[LNUM]; float s = 0.f;
    #pragma unroll
    for (int l = 0; l < LNUM; ++l) { e[l] = expf(lw[l] - m); s += e[l]; }
    #pragma unroll
    for (int l = 0; l < LNUM; ++l) w[l] = e[l] / s;
  }
  __syncthreads();

  const int len = lengths[b];

  float4 sum = make_float4(0.f, 0.f, 0.f, 0.f);
  float4 sq  = make_float4(0.f, 0.f, 0.f, 0.f);

  // thread covers 4 consecutive floats of F: f = 4*tid .. 4*tid+3 (192*4 = 768)
  const float* xb = x + ((size_t)b * SDIM) * LNUM * FDIM + (size_t)threadIdx.x * 4;

  for (int s = t; s < len; s += NT) {
    const float* xs = xb + (size_t)s * LNUM * FDIM;
    float4 word = make_float4(0.f, 0.f, 0.f, 0.f);
    #pragma unroll
    for (int l = 0; l < LNUM; ++l) {
      float4 v = *reinterpret_cast<const float4*>(xs + (size_t)l * FDIM);
      const float wl = w[l];
      word.x = fmaf(wl, v.x, word.x);
      word.y = fmaf(wl, v.y, word.y);
      word.z = fmaf(wl, v.z, word.z);
      word.w = fmaf(wl, v.w, word.w);
    }
    sum.x += word.x; sum.y += word.y; sum.z += word.z; sum.w += word.w;
    sq.x = fmaf(word.x, word.x, sq.x);
    sq.y = fmaf(word.y, word.y, sq.y);
    sq.z = fmaf(word.z, word.z, sq.z);
    sq.w = fmaf(word.w, word.w, sq.w);
  }

  float* p = partial + ((size_t)(b * NT + t) * 2) * FDIM + (size_t)threadIdx.x * 4;
  *reinterpret_cast<float4*>(p) = sum;          // written even when len==0 (ws is poisoned)
  *reinterpret_cast<float4*>(p + FDIM) = sq;
}

// ---------------- Kernel T: fused stats + 3-layer MLP, one block per batch row
__global__ __launch_bounds__(256) void kTail(
    const float* __restrict__ partial, const int* __restrict__ lengths,
    const float* __restrict__ W1, const float* __restrict__ b1,
    const float* __restrict__ W2, const float* __restrict__ b2,
    const float* __restrict__ W3, const float* __restrict__ b3,
    float* __restrict__ out, int NT) {
  const int b = blockIdx.x;
  const int t = threadIdx.x;  // 0..255

  __shared__ float feats[2 * FDIM];  // 6 KB
  __shared__ float h1s[H1DIM];       // 2 KB
  __shared__ float wred[4];

  // ---- 1. reduce NT partial tiles -> mean/std feats (3 features per thread)
  float ms0 = 0.f, ms1 = 0.f, ms2 = 0.f;
  float mq0 = 0.f, mq1 = 0.f, mq2 = 0.f;
  const float* pb = partial + (size_t)b * NT * 2 * FDIM;
  #pragma unroll 4
  for (int tt = 0; tt < NT; ++tt) {
    const float* p = pb + (size_t)tt * 2 * FDIM;
    ms0 += p[t];        ms1 += p[t + 256];        ms2 += p[t + 512];
    mq0 += p[FDIM + t]; mq1 += p[FDIM + t + 256]; mq2 += p[FDIM + t + 512];
  }
  const int n = lengths[b];
  const float fn = (float)n;
  const float inv_n = 1.f / fmaxf(fn, 1.f);
  const float inv_n1 = 1.f / fmaxf(fn - 1.f, 1.f);
  {
    float mean0 = ms0 * inv_n, mean1 = ms1 * inv_n, mean2 = ms2 * inv_n;
    float v0 = (mq0 - fn * mean0 * mean0) * inv_n1;
    float v1 = (mq1 - fn * mean1 * mean1) * inv_n1;
    float v2 = (mq2 - fn * mean2 * mean2) * inv_n1;
    float sd0 = (n > 1) ? sqrtf(fmaxf(v0, 0.f)) : 0.f;
    float sd1 = (n > 1) ? sqrtf(fmaxf(v1, 0.f)) : 0.f;
    float sd2 = (n > 1) ? sqrtf(fmaxf(v2, 0.f)) : 0.f;
    feats[t]        = mean0; feats[t + 256]        = mean1; feats[t + 512]        = mean2;
    feats[FDIM + t] = sd0;   feats[FDIM + t + 256] = sd1;   feats[FDIM + t + 512] = sd2;
  }
  __syncthreads();

  // ---- 2. fc1: thread t computes cols j = 2t, 2t+1 (float2 W1 loads)
  {
    float2 bv = *reinterpret_cast<const float2*>(&b1[2 * t]);
    float a0 = bv.x, a1 = bv.y;
    #pragma unroll 8
    for (int k = 0; k < 2 * FDIM; ++k) {
      float2 wv = *reinterpret_cast<const float2*>(&W1[(size_t)k * H1DIM + 2 * t]);
      const float fk = feats[k];
      a0 = fmaf(fk, wv.x, a0);
      a1 = fmaf(fk, wv.y, a1);
    }
    h1s[2 * t]     = fmaxf(a0, 0.f);
    h1s[2 * t + 1] = fmaxf(a1, 0.f);
  }
  __syncthreads();

  // ---- 3. fc2 + fc3: thread t computes h2[t], then reduce h2 . W3
  float acc = b2[t];
  #pragma unroll 8
  for (int k = 0; k < H1DIM; ++k)
    acc = fmaf(h1s[k], W2[(size_t)k * H2DIM + t], acc);
  const float h2 = fmaxf(acc, 0.f);
  float v = h2 * W3[t];
  #pragma unroll
  for (int off = 32; off > 0; off >>= 1) v += __shfl_down(v, off, 64);
  if ((t & 63) == 0) wred[t >> 6] = v;
  __syncthreads();
  if (t == 0) out[b] = wred[0] + wred[1] + wred[2] + wred[3] + b3[0];
}

extern "C" void kernel_launch(void* const* d_in, const int* in_sizes, int n_in,
                              void* d_out, int out_size, void* d_ws, size_t ws_size,
                              hipStream_t stream) {
  const float* x       = (const float*)d_in[0];
  const int*   lengths = (const int*)  d_in[1];
  const float* lw      = (const float*)d_in[2];
  const float* W1      = (const float*)d_in[3];
  const float* b1      = (const float*)d_in[4];
  const float* W2      = (const float*)d_in[5];
  const float* b2      = (const float*)d_in[6];
  const float* W3      = (const float*)d_in[7];
  const float* b3      = (const float*)d_in[8];
  float* out = (float*)d_out;

  // pick NT (interleave factor over S) to fit workspace
  int NT = 64;
  while ((size_t)BNUM * NT * 2 * FDIM * sizeof(float) > ws_size && NT > 1) NT >>= 1;

  float* partial = (float*)d_ws;

  kA_partials<<<dim3(BNUM * NT), dim3(192), 0, stream>>>(x, lengths, lw, partial, NT);
  kTail<<<dim3(BNUM), dim3(256), 0, stream>>>(partial, lengths, W1, b1, W2, b2, W3, b3, out, NT);
}

// Round 3
// 94.370 us; speedup vs baseline: 1.8072x; 1.7744x over previous
//
#include <hip/hip_runtime.h>
#include <hip/hip_bf16.h>

#define LNUM 13
#define FDIM 768
#define SDIM 512
#define BNUM 32
#define H1DIM 512
#define H2DIM 256

// ---------------- Kernel A: per-tile partial sum / sumsq of layer-weighted word vectors
// Block (b, t) handles s = t, t+NT, t+2NT, ... < len  (balanced within each b)
__global__ __launch_bounds__(192) void kA_partials(
    const float* __restrict__ x, const int* __restrict__ lengths,
    const float* __restrict__ lw, float* __restrict__ partial, int NT) {
  const int b = blockIdx.x / NT;
  const int t = blockIdx.x % NT;

  __shared__ float w[LNUM];
  if (threadIdx.x == 0) {
    float m = lw[0];
    #pragma unroll
    for (int l = 1; l < LNUM; ++l) m = fmaxf(m, lw[l]);
    float e[LNUM]; float s = 0.f;
    #pragma unroll
    for (int l = 0; l < LNUM; ++l) { e[l] = expf(lw[l] - m); s += e[l]; }
    #pragma unroll
    for (int l = 0; l < LNUM; ++l) w[l] = e[l] / s;
  }
  __syncthreads();

  const int len = lengths[b];

  float4 sum = make_float4(0.f, 0.f, 0.f, 0.f);
  float4 sq  = make_float4(0.f, 0.f, 0.f, 0.f);

  const float* xb = x + ((size_t)b * SDIM) * LNUM * FDIM + (size_t)threadIdx.x * 4;

  for (int s = t; s < len; s += NT) {
    const float* xs = xb + (size_t)s * LNUM * FDIM;
    float4 word = make_float4(0.f, 0.f, 0.f, 0.f);
    #pragma unroll
    for (int l = 0; l < LNUM; ++l) {
      float4 v = *reinterpret_cast<const float4*>(xs + (size_t)l * FDIM);
      const float wl = w[l];
      word.x = fmaf(wl, v.x, word.x);
      word.y = fmaf(wl, v.y, word.y);
      word.z = fmaf(wl, v.z, word.z);
      word.w = fmaf(wl, v.w, word.w);
    }
    sum.x += word.x; sum.y += word.y; sum.z += word.z; sum.w += word.w;
    sq.x = fmaf(word.x, word.x, sq.x);
    sq.y = fmaf(word.y, word.y, sq.y);
    sq.z = fmaf(word.z, word.z, sq.z);
    sq.w = fmaf(word.w, word.w, sq.w);
  }

  float* p = partial + ((size_t)(b * NT + t) * 2) * FDIM + (size_t)threadIdx.x * 4;
  *reinterpret_cast<float4*>(p) = sum;   // written even when len==0 (ws is poisoned)
  *reinterpret_cast<float4*>(p + FDIM) = sq;
}

// ---------------- Kernel S: reduce partials -> feats [B, 2F]. grid = B * 3, 256 thr
__global__ __launch_bounds__(256) void kStats(
    const float* __restrict__ partial, const int* __restrict__ lengths,
    float* __restrict__ feats, int NT) {
  const int b = blockIdx.x / 3;
  const int c = blockIdx.x % 3;
  const int f = c * 256 + threadIdx.x;   // 0..767

  float ms = 0.f, mq = 0.f;
  const float* pb = partial + (size_t)b * NT * 2 * FDIM;
  #pragma unroll 16
  for (int tt = 0; tt < NT; ++tt) {
    const float* p = pb + (size_t)tt * 2 * FDIM;
    ms += p[f];
    mq += p[FDIM + f];
  }
  const int n = lengths[b];
  const float fn = (float)n;
  const float mean = ms / fmaxf(fn, 1.f);
  const float var = (mq - fn * mean * mean) / fmaxf(fn - 1.f, 1.f);
  const float sd = (n > 1) ? sqrtf(fmaxf(var, 0.f)) : 0.f;
  feats[(size_t)b * 2 * FDIM + f] = mean;
  feats[(size_t)b * 2 * FDIM + FDIM + f] = sd;
}

// ---------------- Kernel C: h1 = relu(feats @ W1 + b1)
// grid = B * 4 (j-tiles of 128), 512 thr = 128 j-lanes x 4 k-slices
__global__ __launch_bounds__(512) void kFC1(
    const float* __restrict__ feats, const float* __restrict__ W1,
    const float* __restrict__ b1, float* __restrict__ h1) {
  const int b  = blockIdx.x >> 2;
  const int jt = blockIdx.x & 3;
  const int t  = threadIdx.x;
  const int jl = t & 127;
  const int kh = t >> 7;              // 0..3
  const int j  = jt * 128 + jl;

  __shared__ float fs[2 * FDIM];      // 6 KB
  __shared__ float red[4][128];       // 2 KB

  for (int i = t; i < 2 * FDIM; i += 512)
    fs[i] = feats[(size_t)b * 2 * FDIM + i];
  __syncthreads();

  const float* wcol = W1 + (size_t)kh * 384 * H1DIM + j;
  const float* fk = fs + kh * 384;
  float acc = 0.f;
  #pragma unroll 16
  for (int i = 0; i < 384; ++i)
    acc = fmaf(fk[i], wcol[(size_t)i * H1DIM], acc);
  red[kh][jl] = acc;
  __syncthreads();

  if (t < 128) {
    float a = red[0][t] + red[1][t] + red[2][t] + red[3][t] + b1[j - jl + t];
    h1[(size_t)b * H1DIM + jt * 128 + t] = fmaxf(a, 0.f);
  }
}

// ---------------- Kernel D: h2 = relu(h1 @ W2 + b2); out = h2 @ W3 + b3
// grid = B, 512 thr = 256 j-lanes x 2 k-halves
__global__ __launch_bounds__(512) void kFC23(
    const float* __restrict__ h1, const float* __restrict__ W2,
    const float* __restrict__ b2, const float* __restrict__ W3,
    const float* __restrict__ b3, float* __restrict__ out) {
  const int b = blockIdx.x;
  const int t = threadIdx.x;
  const int jl = t & 255;
  const int kh = t >> 8;              // 0..1

  __shared__ float hs[H1DIM];         // 2 KB
  __shared__ float red[2 * H2DIM];    // 2 KB
  __shared__ float wred[8];

  if (t < H1DIM) hs[t] = h1[(size_t)b * H1DIM + t];
  __syncthreads();

  const float* wcol = W2 + (size_t)kh * 256 * H2DIM + jl;
  const float* hk = hs + kh * 256;
  float acc = 0.f;
  #pragma unroll 16
  for (int i = 0; i < 256; ++i)
    acc = fmaf(hk[i], wcol[(size_t)i * H2DIM], acc);
  red[kh * H2DIM + jl] = acc;
  __syncthreads();

  float v = 0.f;
  if (t < H2DIM) {
    const float h2 = fmaxf(red[t] + red[H2DIM + t] + b2[t], 0.f);
    v = h2 * W3[t];
  }
  #pragma unroll
  for (int off = 32; off > 0; off >>= 1) v += __shfl_down(v, off, 64);
  if ((t & 63) == 0) wred[t >> 6] = v;
  __syncthreads();
  if (t == 0) {
    float r = b3[0];
    #pragma unroll
    for (int i = 0; i < 8; ++i) r += wred[i];
    out[b] = r;
  }
}

extern "C" void kernel_launch(void* const* d_in, const int* in_sizes, int n_in,
                              void* d_out, int out_size, void* d_ws, size_t ws_size,
                              hipStream_t stream) {
  const float* x       = (const float*)d_in[0];
  const int*   lengths = (const int*)  d_in[1];
  const float* lw      = (const float*)d_in[2];
  const float* W1      = (const float*)d_in[3];
  const float* b1      = (const float*)d_in[4];
  const float* W2      = (const float*)d_in[5];
  const float* b2      = (const float*)d_in[6];
  const float* W3      = (const float*)d_in[7];
  const float* b3      = (const float*)d_in[8];
  float* out = (float*)d_out;

  int NT = 64;
  for (;;) {
    size_t need = ((size_t)BNUM * NT * 2 * FDIM + (size_t)BNUM * 2 * FDIM +
                   (size_t)BNUM * H1DIM) * sizeof(float);
    if (need <= ws_size || NT == 1) break;
    NT >>= 1;
  }

  float* partial = (float*)d_ws;
  float* feats   = partial + (size_t)BNUM * NT * 2 * FDIM;
  float* h1      = feats + (size_t)BNUM * 2 * FDIM;

  kA_partials<<<dim3(BNUM * NT), dim3(192), 0, stream>>>(x, lengths, lw, partial, NT);
  kStats<<<dim3(BNUM * 3), dim3(256), 0, stream>>>(partial, lengths, feats, NT);
  kFC1<<<dim3(BNUM * 4), dim3(512), 0, stream>>>(feats, W1, b1, h1);
  kFC23<<<dim3(BNUM), dim3(512), 0, stream>>>(h1, W2, b2, W3, b3, out);
}